// Round 4
// baseline (244.524 us; speedup 1.0000x reference)
//
#include <hip/hip_runtime.h>
#include <math.h>

#define CIN   64
#define COUT  128
#define HW    56
#define L_    3136
#define KTOT  6912
#define TH    4            // tile rows
#define TW    8            // tile cols
#define HALO_W 10
#define NPIX  60           // 6 x 10 halo pixels
#define G8_CSTR (NPIX*16)  // 960 B per channel (and per c2-pair in G4)
#define G8_SIZE (8*G8_CSTR)   // 7680
#define G4_SIZE (4*G8_CSTR)   // 3840
#define BUF_SIZE (G8_SIZE+G4_SIZE) // 11520
#define KCHUNK 864         // K elems per 8-channel chunk

#define BP_BYTES (COUT * KTOT * 2)    // 1,769,472
#define PART_OFF BP_BYTES
#define SS_OFF   (BP_BYTES + 2048 * 4)

typedef __attribute__((ext_vector_type(8))) short bf16x8;
typedef __attribute__((ext_vector_type(4))) float f32x4;

__device__ __forceinline__ unsigned short f2bf(float f) {
    unsigned int u = __float_as_uint(f);
    return (unsigned short)((u + 0x7FFFu + ((u >> 16) & 1u)) >> 16);   // RNE
}
__device__ __forceinline__ unsigned int pk2(float a, float b) {
    return (unsigned int)f2bf(a) | ((unsigned int)f2bf(b) << 16);
}

// Evaluate the reference basis for one pixel value and store:
//  g8rec (16B): cubic weights scattered to slots 0..7 (others zero)
//  g4half (8B): {f8, f9, f10, raw x} bf16
__device__ __forceinline__ void eval_store(float xv, char* g8rec, char* g4half) {
    float u  = 1.0f / (1.0f + __expf(-xv));
    float tt = u * 11.0f;
    int s = (int)floorf(tt);
    s = (s > 10) ? 10 : s;
    float xf  = tt - (float)s;
    float x2  = xf * xf, x3 = x2 * xf;
    float omx = 1.0f - xf;
    const float i6 = 1.0f / 6.0f;
    float w3 = x3 * i6;
    float w2 = fmaf(fmaf(fmaf(-3.0f, xf, 3.0f), xf, 3.0f), xf, 1.0f) * i6;
    float w1 = fmaf(fmaf(3.0f, xf, -6.0f), x2, 4.0f) * i6;
    float w0 = omx * omx * omx * i6;

    *reinterpret_cast<uint4*>(g8rec) = (uint4){0u, 0u, 0u, 0u};
    unsigned short* rec = reinterpret_cast<unsigned short*>(g8rec);
    {
        int j;
        j = s - 3; if (j >= 0 && j < 8) rec[j] = f2bf(w0);
        j = s - 2; if (j >= 0 && j < 8) rec[j] = f2bf(w1);
        j = s - 1; if (j >= 0 && j < 8) rec[j] = f2bf(w2);
        j = s;     if (j >= 0 && j < 8) rec[j] = f2bf(w3);
    }
    float y = tt - 8.0f;
    float f8 = 0.0f;
    f8 = (s == 8)  ? 0.5f * y * y : f8;
    f8 = (s == 9)  ? 0.5f * fmaf(-2.0f * y, y, fmaf(6.0f, y, -3.0f)) : f8;
    f8 = (s == 10) ? 0.5f * (3.0f - y) * (3.0f - y) : f8;
    float z = tt - 9.0f;
    float f9 = 0.0f;
    f9 = (s == 9)  ? z : f9;
    f9 = (s == 10) ? 2.0f - z : f9;
    float f10 = (s == 10) ? 1.0f : 0.0f;
    *reinterpret_cast<uint2*>(g4half) = make_uint2(pk2(f8, f9), pk2(f10, xv));
}

// Pack B[o][kk] bf16 in the k_main K-order:
// kk = ch*864 + k*96 + ph*32 + e ; ph<2: c=ch*8+ph*4+(e>>3), n=e&7
// ph==2: c=ch*8+(e>>3)*2+((e&7)>>2), n=8+(e&3); n==11 -> conv_w
__global__ __launch_bounds__(256) void k_packB(const float* __restrict__ cp,
                                               const float* __restrict__ w,
                                               unsigned short* __restrict__ Bp) {
    int id = blockIdx.x * 256 + threadIdx.x;
    if (id >= COUT * KTOT) return;
    int o  = id / KTOT, kk = id - o * KTOT;
    int ch = kk / KCHUNK, r = kk - ch * KCHUNK;
    int k  = r / 96, r2 = r - k * 96;
    int ph = r2 >> 5, e = r2 & 31;
    int c, n;
    if (ph < 2) { c = ch * 8 + ph * 4 + (e >> 3); n = e & 7; }
    else        { int sub = e & 7; c = ch * 8 + (e >> 3) * 2 + (sub >> 2); n = 8 + (sub & 3); }
    float v;
    if (n < 11) v = cp[(((size_t)o * CIN + c) * 9 + k) * 11 + n];
    else        v = w[((size_t)o * CIN + c) * 9 + k];
    Bp[id] = f2bf(v);
}

__global__ __launch_bounds__(256, 3) void k_main(const float* __restrict__ x,
                                                 const unsigned short* __restrict__ Bp,
                                                 const float* __restrict__ bias,
                                                 float* __restrict__ out) {
    __shared__ char lds[2 * BUF_SIZE];

    const int bid  = blockIdx.x;
    const int b    = bid / 98;            // 98 tiles per image (14 x 7)
    const int tile = bid - b * 98;
    const int th   = tile / 7;            // 0..13
    const int tw   = tile - th * 7;       // 0..6
    const int t    = threadIdx.x;
    const int lane = t & 63;
    const int wid  = t >> 6;              // 0..3 : o-quarter

    // ---- staging roles: round r covers channels r*4 + (t>>6), pixel t&63 ----
    const int sc    = t >> 6;             // 0..3
    const int spix  = t & 63;
    const int sph   = spix / 10, spw = spix - sph * 10;
    const bool svalid = (spix < NPIX);
    const int hg = th * TH - 1 + sph;
    const int wg = tw * TW - 1 + spw;
    const bool inb = svalid && (hg >= 0) && (hg < HW) && (wg >= 0) && (wg < HW);
    const size_t xbase = (size_t)b * CIN * L_ + (size_t)hg * HW + wg;

    // ---- MFMA lane invariants ----
    const int q   = lane >> 4;            // rec-select group
    const int r15 = lane & 15;
    int P[2];
#pragma unroll
    for (int mi = 0; mi < 2; mi++) {
        int arow = mi * 16 + r15;
        int lh = arow >> 3, lw = arow & 7;
        P[mi] = (lh * HALO_W + lw) * 16 + q * G8_CSTR;
    }
    const int obase = wid * 32 + r15;
    const unsigned short* bc0 = Bp + (size_t)obase * KTOT + q * 8;
    const unsigned short* bc1 = bc0 + (size_t)16 * KTOT;

    f32x4 acc[2][2];
#pragma unroll
    for (int mi = 0; mi < 2; mi++)
#pragma unroll
        for (int ni = 0; ni < 2; ni++) acc[mi][ni] = (f32x4){0.f, 0.f, 0.f, 0.f};

    // ---- B register pipeline: 9 steps deep (27 % 9 == 0 -> static slots) ----
    bf16x8 breg0[9], breg1[9];
#pragma unroll
    for (int s = 0; s < 9; s++) {
        breg0[s] = *reinterpret_cast<const bf16x8*>(bc0 + s * 32);
        breg1[s] = *reinterpret_cast<const bf16x8*>(bc1 + s * 32);
    }

    float xv[2];
    // prefetch + eval chunk 0
#pragma unroll
    for (int r = 0; r < 2; r++) {
        int c = r * 4 + sc;
        xv[r] = inb ? x[xbase + (size_t)c * L_] : 0.0f;
    }
    if (svalid) {
#pragma unroll
        for (int r = 0; r < 2; r++) {
            int c = r * 4 + sc;
            eval_store(xv[r], &lds[c * G8_CSTR + spix * 16],
                       &lds[G8_SIZE + (c >> 1) * G8_CSTR + spix * 16 + (c & 1) * 8]);
        }
    }
    __syncthreads();

#pragma unroll 1
    for (int ch = 0; ch < 8; ch++) {
        char* abuf = &lds[(ch & 1) * BUF_SIZE];
        // issue next chunk's x loads early (latency hides under MFMA)
        if (ch < 7) {
#pragma unroll
            for (int r = 0; r < 2; r++) {
                int c = (ch + 1) * 8 + r * 4 + sc;
                xv[r] = inb ? x[xbase + (size_t)c * L_] : 0.0f;
            }
        }
        const unsigned short* bn0 = (ch < 7) ? (bc0 + KCHUNK) : bc0;
        const unsigned short* bn1 = (ch < 7) ? (bc1 + KCHUNK) : bc1;

        // ---- A register pipeline: 2 steps ahead (rotating depth 3) ----
        bf16x8 areg0[3], areg1[3];
        auto aread = [&](int s, bf16x8& a0, bf16x8& a1) {
            int k = s / 3, ph = s - k * 3;
            int ki = k / 3, kj = k - ki * 3;
            int poff = (ki * HALO_W + kj) * 16;
            int aoff = (ph == 2) ? (G8_SIZE + poff) : (ph * 4 * G8_CSTR + poff);
            a0 = *reinterpret_cast<const bf16x8*>(abuf + P[0] + aoff);
            a1 = *reinterpret_cast<const bf16x8*>(abuf + P[1] + aoff);
        };
        aread(0, areg0[0], areg1[0]);
        aread(1, areg0[1], areg1[1]);

#pragma unroll
        for (int s = 0; s < 27; s++) {
            if (s + 2 < 27) aread(s + 2, areg0[(s + 2) % 3], areg1[(s + 2) % 3]);
            const int bs = s % 9;
            bf16x8 af0 = areg0[s % 3], af1 = areg1[s % 3];
            acc[0][0] = __builtin_amdgcn_mfma_f32_16x16x32_bf16(af0, breg0[bs], acc[0][0], 0, 0, 0);
            acc[1][0] = __builtin_amdgcn_mfma_f32_16x16x32_bf16(af1, breg0[bs], acc[1][0], 0, 0, 0);
            acc[0][1] = __builtin_amdgcn_mfma_f32_16x16x32_bf16(af0, breg1[bs], acc[0][1], 0, 0, 0);
            acc[1][1] = __builtin_amdgcn_mfma_f32_16x16x32_bf16(af1, breg1[bs], acc[1][1], 0, 0, 0);
            // refill this slot with step s+9 (crosses into next chunk for s>=18)
            const unsigned short* r0 = (s < 18) ? (bc0 + (s + 9) * 32) : (bn0 + (s - 18) * 32);
            const unsigned short* r1 = (s < 18) ? (bc1 + (s + 9) * 32) : (bn1 + (s - 18) * 32);
            breg0[bs] = *reinterpret_cast<const bf16x8*>(r0);
            breg1[bs] = *reinterpret_cast<const bf16x8*>(r1);
        }

        // evaluate + write next chunk AFTER this chunk's MFMAs
        if (ch < 7 && svalid) {
            char* nbuf = &lds[((ch + 1) & 1) * BUF_SIZE];
#pragma unroll
            for (int r = 0; r < 2; r++) {
                int c = r * 4 + sc;
                eval_store(xv[r], &nbuf[c * G8_CSTR + spix * 16],
                           &nbuf[G8_SIZE + (c >> 1) * G8_CSTR + spix * 16 + (c & 1) * 8]);
            }
        }
        __syncthreads();
        bc0 = bn0; bc1 = bn1;
    }

    // ---- epilogue: C frag col=lane&15 -> o, row=(lane>>4)*4+r -> l ----
#pragma unroll
    for (int ni = 0; ni < 2; ni++) {
        int o = obase + ni * 16;
        float bv = bias[o];
#pragma unroll
        for (int mi = 0; mi < 2; mi++) {
            int crow = mi * 16 + q * 4;
            int lh = crow >> 3, lw = crow & 7;
            int lg = (th * TH + lh) * HW + tw * TW + lw;
            float4 v;
            v.x = acc[mi][ni][0] + bv;
            v.y = acc[mi][ni][1] + bv;
            v.z = acc[mi][ni][2] + bv;
            v.w = acc[mi][ni][3] + bv;
            *reinterpret_cast<float4*>(&out[(size_t)(b * COUT + o) * L_ + lg]) = v;
        }
    }
}

// Partial sums per (b,o) slab.
__global__ __launch_bounds__(256) void k_part(const float* __restrict__ s,
                                              float* __restrict__ part) {
    const int slab = blockIdx.x;
    const float4* p4 = reinterpret_cast<const float4*>(s + (size_t)slab * L_);
    const int t = threadIdx.x;
    float sum = 0.f, sq = 0.f;
    for (int i = t; i < L_ / 4; i += 256) {
        float4 v = p4[i];
        sum += v.x + v.y + v.z + v.w;
        sq  += v.x * v.x + v.y * v.y + v.z * v.z + v.w * v.w;
    }
    __shared__ float rs[256], rq[256];
    rs[t] = sum; rq[t] = sq;
    __syncthreads();
    for (int off = 128; off > 0; off >>= 1) {
        if (t < off) { rs[t] += rs[t + off]; rq[t] += rq[t + off]; }
        __syncthreads();
    }
    if (t == 0) { part[slab] = rs[0]; part[1024 + slab] = rq[0]; }
}

__global__ __launch_bounds__(128) void k_final(const float* __restrict__ part,
                                               const float* __restrict__ gamma,
                                               const float* __restrict__ beta,
                                               float* __restrict__ ss) {
    int o = threadIdx.x;
    float sum = 0.f, sq = 0.f;
#pragma unroll
    for (int b = 0; b < 8; b++) {
        sum += part[b * COUT + o];
        sq  += part[1024 + b * COUT + o];
    }
    float n = (float)(8 * L_);
    float mean = sum / n;
    float var  = sq / n - mean * mean;
    float scale = gamma[o] * rsqrtf(var + 1e-5f);
    ss[o]        = scale;
    ss[COUT + o] = beta[o] - mean * scale;
}

__global__ __launch_bounds__(256) void k_norm(float* __restrict__ out,
                                              const float* __restrict__ ss) {
    const int n4 = 8 * COUT * L_ / 4;
    for (int i = blockIdx.x * 256 + threadIdx.x; i < n4; i += gridDim.x * 256) {
        int o = ((i * 4) / L_) & (COUT - 1);
        float sc = ss[o], sh = ss[COUT + o];
        float4 v = reinterpret_cast<float4*>(out)[i];
        v.x = fmaf(v.x, sc, sh);
        v.y = fmaf(v.y, sc, sh);
        v.z = fmaf(v.z, sc, sh);
        v.w = fmaf(v.w, sc, sh);
        reinterpret_cast<float4*>(out)[i] = v;
    }
}

extern "C" void kernel_launch(void* const* d_in, const int* in_sizes, int n_in,
                              void* d_out, int out_size, void* d_ws, size_t ws_size,
                              hipStream_t stream) {
    const float* x     = (const float*)d_in[0];
    const float* cp    = (const float*)d_in[1];
    const float* w     = (const float*)d_in[2];
    const float* bias  = (const float*)d_in[3];
    const float* gamma = (const float*)d_in[4];
    const float* beta  = (const float*)d_in[5];
    float* out = (float*)d_out;

    unsigned short* Bp = (unsigned short*)d_ws;
    float* part = (float*)((char*)d_ws + PART_OFF);
    float* ss   = (float*)((char*)d_ws + SS_OFF);

    k_packB<<<(COUT * KTOT + 255) / 256, 256, 0, stream>>>(cp, w, Bp);
    k_main<<<8 * 98, 256, 0, stream>>>(x, Bp, bias, out);
    k_part<<<1024, 256, 0, stream>>>(out, part);
    k_final<<<1, 128, 0, stream>>>(part, gamma, beta, ss);
    k_norm<<<2048, 256, 0, stream>>>(out, ss);
}

// Round 5
// 228.159 us; speedup vs baseline: 1.0717x; 1.0717x over previous
//
#include <hip/hip_runtime.h>
#include <math.h>

#define CIN   64
#define COUT  128
#define HW    56
#define L_    3136
#define KTOT  6912
#define TH    4            // tile rows
#define TW    8            // tile cols
#define HALO_W 10
#define NPIX  60           // 6 x 10 halo pixels
#define G8_CSTR (NPIX*16)  // 960 B per channel (and per c2-pair in G4)
#define G8_SIZE (8*G8_CSTR)   // 7680
#define G4_SIZE (4*G8_CSTR)   // 3840
#define BUF_SIZE (G8_SIZE+G4_SIZE) // 11520
#define KCHUNK 864         // K elems per 8-channel chunk

#define BP_BYTES (COUT * KTOT * 2)        // 1,769,472
#define PART_OFF (BP_BYTES + 16384)       // 16KB pad: B-pipeline prefetches past end
#define SS_OFF   (PART_OFF + 2048 * 4)

typedef __attribute__((ext_vector_type(8))) short bf16x8;
typedef __attribute__((ext_vector_type(4))) float f32x4;
typedef unsigned long long u64;

#define BLOAD(dst, addr) \
    asm volatile("global_load_dwordx4 %0, %1, off" : "=v"(dst) : "v"(addr))
#define XLOAD(dst, addr) \
    asm volatile("global_load_dword %0, %1, off" : "=v"(dst) : "v"(addr))

__device__ __forceinline__ unsigned short f2bf(float f) {
    unsigned int u = __float_as_uint(f);
    return (unsigned short)((u + 0x7FFFu + ((u >> 16) & 1u)) >> 16);   // RNE
}
__device__ __forceinline__ unsigned int pk2(float a, float b) {
    return (unsigned int)f2bf(a) | ((unsigned int)f2bf(b) << 16);
}

// Reference basis for one pixel: g8rec (16B) = cubic weights scattered to
// slots 0..7; g4half (8B) = {f8, f9, f10, raw x} bf16.
__device__ __forceinline__ void eval_store(float xv, char* g8rec, char* g4half) {
    float u  = 1.0f / (1.0f + __expf(-xv));
    float tt = u * 11.0f;
    int s = (int)floorf(tt);
    s = (s > 10) ? 10 : s;
    float xf  = tt - (float)s;
    float x2  = xf * xf, x3 = x2 * xf;
    float omx = 1.0f - xf;
    const float i6 = 1.0f / 6.0f;
    float w3 = x3 * i6;
    float w2 = fmaf(fmaf(fmaf(-3.0f, xf, 3.0f), xf, 3.0f), xf, 1.0f) * i6;
    float w1 = fmaf(fmaf(3.0f, xf, -6.0f), x2, 4.0f) * i6;
    float w0 = omx * omx * omx * i6;

    *reinterpret_cast<uint4*>(g8rec) = (uint4){0u, 0u, 0u, 0u};
    unsigned short* rec = reinterpret_cast<unsigned short*>(g8rec);
    {
        int j;
        j = s - 3; if (j >= 0 && j < 8) rec[j] = f2bf(w0);
        j = s - 2; if (j >= 0 && j < 8) rec[j] = f2bf(w1);
        j = s - 1; if (j >= 0 && j < 8) rec[j] = f2bf(w2);
        j = s;     if (j >= 0 && j < 8) rec[j] = f2bf(w3);
    }
    float y = tt - 8.0f;
    float f8 = 0.0f;
    f8 = (s == 8)  ? 0.5f * y * y : f8;
    f8 = (s == 9)  ? 0.5f * fmaf(-2.0f * y, y, fmaf(6.0f, y, -3.0f)) : f8;
    f8 = (s == 10) ? 0.5f * (3.0f - y) * (3.0f - y) : f8;
    float z = tt - 9.0f;
    float f9 = 0.0f;
    f9 = (s == 9)  ? z : f9;
    f9 = (s == 10) ? 2.0f - z : f9;
    float f10 = (s == 10) ? 1.0f : 0.0f;
    *reinterpret_cast<uint2*>(g4half) = make_uint2(pk2(f8, f9), pk2(f10, xv));
}

// Pack B[o][kk] bf16 (same K-order as R3/R4).
__global__ __launch_bounds__(256) void k_packB(const float* __restrict__ cp,
                                               const float* __restrict__ w,
                                               unsigned short* __restrict__ Bp) {
    int id = blockIdx.x * 256 + threadIdx.x;
    if (id >= COUT * KTOT) return;
    int o  = id / KTOT, kk = id - o * KTOT;
    int ch = kk / KCHUNK, r = kk - ch * KCHUNK;
    int k  = r / 96, r2 = r - k * 96;
    int ph = r2 >> 5, e = r2 & 31;
    int c, n;
    if (ph < 2) { c = ch * 8 + ph * 4 + (e >> 3); n = e & 7; }
    else        { int sub = e & 7; c = ch * 8 + (e >> 3) * 2 + (sub >> 2); n = 8 + (sub & 3); }
    float v;
    if (n < 11) v = cp[(((size_t)o * CIN + c) * 9 + k) * 11 + n];
    else        v = w[((size_t)o * CIN + c) * 9 + k];
    Bp[id] = f2bf(v);
}

__global__ __launch_bounds__(256, 3) void k_main(const float* __restrict__ x,
                                                 const unsigned short* __restrict__ Bp,
                                                 const float* __restrict__ bias,
                                                 float* __restrict__ out) {
    __shared__ char lds[2 * BUF_SIZE];

    const int bid  = blockIdx.x;
    const int b    = bid / 98;            // 98 tiles per image (14 x 7)
    const int tile = bid - b * 98;
    const int th   = tile / 7;
    const int tw   = tile - th * 7;
    const int t    = threadIdx.x;
    const int lane = t & 63;
    const int wid  = t >> 6;              // 0..3 : o-quarter

    // staging roles
    const int sc    = t >> 6;             // 0..3
    const int spix  = t & 63;
    const int sph   = spix / 10, spw = spix - sph * 10;
    const bool svalid = (spix < NPIX);
    const int hg = th * TH - 1 + sph;
    const int wg = tw * TW - 1 + spw;
    const bool inb = svalid && (hg >= 0) && (hg < HW) && (wg >= 0) && (wg < HW);
    const size_t xbase = (size_t)b * CIN * L_ + (size_t)hg * HW + wg;

    // MFMA lane invariants
    const int q   = lane >> 4;
    const int r15 = lane & 15;
    int P[2];
#pragma unroll
    for (int mi = 0; mi < 2; mi++) {
        int arow = mi * 16 + r15;
        int lh = arow >> 3, lw = arow & 7;
        P[mi] = (lh * HALO_W + lw) * 16 + q * G8_CSTR;
    }
    const int obase = wid * 32 + r15;

    // B running pointers (bytes); each K-step of 32 elems = 64B stride
    u64 pa0 = (u64)Bp + ((u64)obase * KTOT + (u64)q * 8) * 2;
    u64 pa1 = pa0 + (u64)16 * KTOT * 2;

    // x running pointers: chunk ch loads channels (ch+1)*8 + {sc, 4+sc}
    const u64 xadv = inb ? (u64)8 * L_ * 4 : 0;
    u64 px0 = inb ? ((u64)x + ((u64)xbase + (size_t)sc * L_) * 4)       : (u64)x;
    u64 px1 = inb ? ((u64)x + ((u64)xbase + (size_t)(4 + sc) * L_) * 4) : (u64)x;

    f32x4 acc[2][2];
#pragma unroll
    for (int mi = 0; mi < 2; mi++)
#pragma unroll
        for (int ni = 0; ni < 2; ni++) acc[mi][ni] = (f32x4){0.f, 0.f, 0.f, 0.f};

    // ---- chunk-0 x loads + eval (no asm B loads in flight yet) ----
    float xa, xb;
    XLOAD(xa, px0);
    XLOAD(xb, px1);
    px0 += xadv; px1 += xadv;            // now point at chunk-1 channels
    asm volatile("s_waitcnt vmcnt(0)");
    __builtin_amdgcn_sched_barrier(0);
    if (svalid) {
        float va = inb ? xa : 0.0f, vb = inb ? xb : 0.0f;
        eval_store(va, &lds[sc * G8_CSTR + spix * 16],
                   &lds[G8_SIZE + (sc >> 1) * G8_CSTR + spix * 16 + (sc & 1) * 8]);
        eval_store(vb, &lds[(4 + sc) * G8_CSTR + spix * 16],
                   &lds[G8_SIZE + ((4 + sc) >> 1) * G8_CSTR + spix * 16 + ((4 + sc) & 1) * 8]);
    }
    asm volatile("s_waitcnt lgkmcnt(0)");
    __builtin_amdgcn_s_barrier();

    // ---- B pipeline prologue: 9 pairs in flight ----
    bf16x8 breg0[9], breg1[9];
#pragma unroll
    for (int s = 0; s < 9; s++) {
        BLOAD(breg0[s], pa0);
        BLOAD(breg1[s], pa1);
        pa0 += 64; pa1 += 64;
    }

#pragma unroll 1
    for (int ch = 0; ch < 8; ch++) {
        // x pair for chunk ch+1 (dummy reload on ch==7 keeps vmcnt uniform)
        XLOAD(xa, px0);
        XLOAD(xb, px1);
        px0 += xadv; px1 += xadv;

        char* abuf = &lds[(ch & 1) * BUF_SIZE];
        char* nbuf = &lds[((ch + 1) & 1) * BUF_SIZE];

        bf16x8 areg0[3], areg1[3];
        auto aread = [&](int s, bf16x8& a0, bf16x8& a1) {
            int k = s / 3, ph = s - k * 3;
            int ki = k / 3, kj = k - ki * 3;
            int poff = (ki * HALO_W + kj) * 16;
            int aoff = (ph == 2) ? (G8_SIZE + poff) : (ph * 4 * G8_CSTR + poff);
            a0 = *reinterpret_cast<const bf16x8*>(abuf + P[0] + aoff);
            a1 = *reinterpret_cast<const bf16x8*>(abuf + P[1] + aoff);
        };
        aread(0, areg0[0], areg1[0]);
        aread(1, areg0[1], areg1[1]);

#pragma unroll
        for (int s = 0; s < 27; s++) {
            if (s + 2 < 27) aread(s + 2, areg0[(s + 2) % 3], areg1[(s + 2) % 3]);
            // outstanding: 9 B-pairs (18) + this chunk's x pair (2) = 20;
            // retire the 2 oldest = the B pair this step consumes.
            asm volatile("s_waitcnt vmcnt(18)");
            __builtin_amdgcn_sched_barrier(0);
            const int bs = s % 9;
            bf16x8 af0 = areg0[s % 3], af1 = areg1[s % 3];
            acc[0][0] = __builtin_amdgcn_mfma_f32_16x16x32_bf16(af0, breg0[bs], acc[0][0], 0, 0, 0);
            acc[1][0] = __builtin_amdgcn_mfma_f32_16x16x32_bf16(af1, breg0[bs], acc[1][0], 0, 0, 0);
            acc[0][1] = __builtin_amdgcn_mfma_f32_16x16x32_bf16(af0, breg1[bs], acc[0][1], 0, 0, 0);
            acc[1][1] = __builtin_amdgcn_mfma_f32_16x16x32_bf16(af1, breg1[bs], acc[1][1], 0, 0, 0);
            // refill consumed slot for step s+9 (reads run 14.3KB past Bp end
            // on the tail — covered by the 16KB ws pad, values never consumed)
            BLOAD(breg0[bs], pa0);
            BLOAD(breg1[bs], pa1);
            pa0 += 64; pa1 += 64;
        }

        // x pair has arrived when <=18 remain (it predates this chunk's refills)
        asm volatile("s_waitcnt vmcnt(18)");
        __builtin_amdgcn_sched_barrier(0);
        if (ch < 7 && svalid) {
            float va = inb ? xa : 0.0f, vb = inb ? xb : 0.0f;
            eval_store(va, &nbuf[sc * G8_CSTR + spix * 16],
                       &nbuf[G8_SIZE + (sc >> 1) * G8_CSTR + spix * 16 + (sc & 1) * 8]);
            eval_store(vb, &nbuf[(4 + sc) * G8_CSTR + spix * 16],
                       &nbuf[G8_SIZE + ((4 + sc) >> 1) * G8_CSTR + spix * 16 + ((4 + sc) & 1) * 8]);
        }
        asm volatile("s_waitcnt lgkmcnt(0)");
        __builtin_amdgcn_s_barrier();
    }

    asm volatile("s_waitcnt vmcnt(0)");   // drain tail prefetches

    // ---- epilogue ----
#pragma unroll
    for (int ni = 0; ni < 2; ni++) {
        int o = obase + ni * 16;
        float bv = bias[o];
#pragma unroll
        for (int mi = 0; mi < 2; mi++) {
            int crow = mi * 16 + q * 4;
            int lh = crow >> 3, lw = crow & 7;
            int lg = (th * TH + lh) * HW + tw * TW + lw;
            float4 v;
            v.x = acc[mi][ni][0] + bv;
            v.y = acc[mi][ni][1] + bv;
            v.z = acc[mi][ni][2] + bv;
            v.w = acc[mi][ni][3] + bv;
            *reinterpret_cast<float4*>(&out[(size_t)(b * COUT + o) * L_ + lg]) = v;
        }
    }
}

// Partial sums per (b,o) slab.
__global__ __launch_bounds__(256) void k_part(const float* __restrict__ s,
                                              float* __restrict__ part) {
    const int slab = blockIdx.x;
    const float4* p4 = reinterpret_cast<const float4*>(s + (size_t)slab * L_);
    const int t = threadIdx.x;
    float sum = 0.f, sq = 0.f;
    for (int i = t; i < L_ / 4; i += 256) {
        float4 v = p4[i];
        sum += v.x + v.y + v.z + v.w;
        sq  += v.x * v.x + v.y * v.y + v.z * v.z + v.w * v.w;
    }
    __shared__ float rs[256], rq[256];
    rs[t] = sum; rq[t] = sq;
    __syncthreads();
    for (int off = 128; off > 0; off >>= 1) {
        if (t < off) { rs[t] += rs[t + off]; rq[t] += rq[t + off]; }
        __syncthreads();
    }
    if (t == 0) { part[slab] = rs[0]; part[1024 + slab] = rq[0]; }
}

__global__ __launch_bounds__(128) void k_final(const float* __restrict__ part,
                                               const float* __restrict__ gamma,
                                               const float* __restrict__ beta,
                                               float* __restrict__ ss) {
    int o = threadIdx.x;
    float sum = 0.f, sq = 0.f;
#pragma unroll
    for (int b = 0; b < 8; b++) {
        sum += part[b * COUT + o];
        sq  += part[1024 + b * COUT + o];
    }
    float n = (float)(8 * L_);
    float mean = sum / n;
    float var  = sq / n - mean * mean;
    float scale = gamma[o] * rsqrtf(var + 1e-5f);
    ss[o]        = scale;
    ss[COUT + o] = beta[o] - mean * scale;
}

__global__ __launch_bounds__(256) void k_norm(float* __restrict__ out,
                                              const float* __restrict__ ss) {
    const int n4 = 8 * COUT * L_ / 4;
    for (int i = blockIdx.x * 256 + threadIdx.x; i < n4; i += gridDim.x * 256) {
        int o = ((i * 4) / L_) & (COUT - 1);
        float sc = ss[o], sh = ss[COUT + o];
        float4 v = reinterpret_cast<float4*>(out)[i];
        v.x = fmaf(v.x, sc, sh);
        v.y = fmaf(v.y, sc, sh);
        v.z = fmaf(v.z, sc, sh);
        v.w = fmaf(v.w, sc, sh);
        reinterpret_cast<float4*>(out)[i] = v;
    }
}

extern "C" void kernel_launch(void* const* d_in, const int* in_sizes, int n_in,
                              void* d_out, int out_size, void* d_ws, size_t ws_size,
                              hipStream_t stream) {
    const float* x     = (const float*)d_in[0];
    const float* cp    = (const float*)d_in[1];
    const float* w     = (const float*)d_in[2];
    const float* bias  = (const float*)d_in[3];
    const float* gamma = (const float*)d_in[4];
    const float* beta  = (const float*)d_in[5];
    float* out = (float*)d_out;

    unsigned short* Bp = (unsigned short*)d_ws;
    float* part = (float*)((char*)d_ws + PART_OFF);
    float* ss   = (float*)((char*)d_ws + SS_OFF);

    k_packB<<<(COUT * KTOT + 255) / 256, 256, 0, stream>>>(cp, w, Bp);
    k_main<<<8 * 98, 256, 0, stream>>>(x, Bp, bias, out);
    k_part<<<1024, 256, 0, stream>>>(out, part);
    k_final<<<1, 128, 0, stream>>>(part, gamma, beta, ss);
    k_norm<<<2048, 256, 0, stream>>>(out, ss);
}

// Round 6
// 138.113 us; speedup vs baseline: 1.7705x; 1.6520x over previous
//
#include <hip/hip_runtime.h>
#include <math.h>

#define CIN   64
#define COUT  128
#define HW    56
#define L_    3136
#define KTOT  6912
#define TH    4            // tile rows
#define TW    8            // tile cols
#define HALO_W 10
#define NPIX  60           // 6 x 10 halo pixels
#define G8_CSTR (NPIX*16)  // 960 B per channel (and per c2-pair in G4)
#define G8_SIZE (8*G8_CSTR)   // 7680
#define G4_SIZE (4*G8_CSTR)   // 3840
#define BUF_SIZE (G8_SIZE+G4_SIZE) // 11520
#define NSTEP 216          // total K-steps of 32

#define BP_BYTES (COUT * KTOT * 2)        // 1,769,472
#define PART_OFF (BP_BYTES + 73728)       // 72KB pad: tail prefetch reads 8 steps past end
#define SS_OFF   (PART_OFF + 2048 * 4)

typedef __attribute__((ext_vector_type(8))) short bf16x8;
typedef __attribute__((ext_vector_type(4))) float f32x4;
typedef unsigned long long u64;

#define BLOAD(dst, addr) \
    asm volatile("global_load_dwordx4 %0, %1, off" : "=v"(dst) : "v"(addr))
#define XLOAD(dst, addr) \
    asm volatile("global_load_dword %0, %1, off" : "=v"(dst) : "v"(addr))

__device__ __forceinline__ unsigned short f2bf(float f) {
    unsigned int u = __float_as_uint(f);
    return (unsigned short)((u + 0x7FFFu + ((u >> 16) & 1u)) >> 16);   // RNE
}
__device__ __forceinline__ unsigned int pk2(float a, float b) {
    return (unsigned int)f2bf(a) | ((unsigned int)f2bf(b) << 16);
}

// Reference basis for one pixel: g8rec (16B) = cubic weights scattered to
// slots 0..7; g4half (8B) = {f8, f9, f10, raw x} bf16.
__device__ __forceinline__ void eval_store(float xv, char* g8rec, char* g4half) {
    float u  = 1.0f / (1.0f + __expf(-xv));
    float tt = u * 11.0f;
    int s = (int)floorf(tt);
    s = (s > 10) ? 10 : s;
    float xf  = tt - (float)s;
    float x2  = xf * xf, x3 = x2 * xf;
    float omx = 1.0f - xf;
    const float i6 = 1.0f / 6.0f;
    float w3 = x3 * i6;
    float w2 = fmaf(fmaf(fmaf(-3.0f, xf, 3.0f), xf, 3.0f), xf, 1.0f) * i6;
    float w1 = fmaf(fmaf(3.0f, xf, -6.0f), x2, 4.0f) * i6;
    float w0 = omx * omx * omx * i6;

    *reinterpret_cast<uint4*>(g8rec) = (uint4){0u, 0u, 0u, 0u};
    unsigned short* rec = reinterpret_cast<unsigned short*>(g8rec);
    {
        int j;
        j = s - 3; if (j >= 0 && j < 8) rec[j] = f2bf(w0);
        j = s - 2; if (j >= 0 && j < 8) rec[j] = f2bf(w1);
        j = s - 1; if (j >= 0 && j < 8) rec[j] = f2bf(w2);
        j = s;     if (j >= 0 && j < 8) rec[j] = f2bf(w3);
    }
    float y = tt - 8.0f;
    float f8 = 0.0f;
    f8 = (s == 8)  ? 0.5f * y * y : f8;
    f8 = (s == 9)  ? 0.5f * fmaf(-2.0f * y, y, fmaf(6.0f, y, -3.0f)) : f8;
    f8 = (s == 10) ? 0.5f * (3.0f - y) * (3.0f - y) : f8;
    float z = tt - 9.0f;
    float f9 = 0.0f;
    f9 = (s == 9)  ? z : f9;
    f9 = (s == 10) ? 2.0f - z : f9;
    float f10 = (s == 10) ? 1.0f : 0.0f;
    *reinterpret_cast<uint2*>(g4half) = make_uint2(pk2(f8, f9), pk2(f10, xv));
}

// Pack B in DENSE per-(kstep,o) 64B units: Bp[kstep][o][e32], e32=0..31.
// kstep = ch*27 + ktap*3 + ph. e32 -> (c,n) as before:
//   ph<2 : c = ch*8 + ph*4 + (e32>>3), n = e32&7
//   ph==2: sub=e32&7; c = ch*8 + (e32>>3)*2 + (sub>>2), n = 8+(sub&3); n==11 -> conv_w
__global__ __launch_bounds__(256) void k_packB(const float* __restrict__ cp,
                                               const float* __restrict__ w,
                                               unsigned short* __restrict__ Bp) {
    int idx = blockIdx.x * 256 + threadIdx.x;
    if (idx >= COUT * KTOT) return;
    int kstep = idx >> 12;            // /4096 (128 o * 32 e)
    int rem   = idx & 4095;
    int o     = rem >> 5;
    int e32   = rem & 31;
    int ch = kstep / 27, sc = kstep - ch * 27;
    int ktap = sc / 3, ph = sc - ktap * 3;
    int c, n;
    if (ph < 2) { c = ch * 8 + ph * 4 + (e32 >> 3); n = e32 & 7; }
    else        { int sub = e32 & 7; c = ch * 8 + (e32 >> 3) * 2 + (sub >> 2); n = 8 + (sub & 3); }
    float v;
    if (n < 11) v = cp[(((size_t)o * CIN + c) * 9 + ktap) * 11 + n];
    else        v = w[((size_t)o * CIN + c) * 9 + ktap];
    Bp[idx] = f2bf(v);
}

__global__ __launch_bounds__(256, 3) void k_main(const float* __restrict__ x,
                                                 const unsigned short* __restrict__ Bp,
                                                 const float* __restrict__ bias,
                                                 float* __restrict__ out) {
    __shared__ char lds[2 * BUF_SIZE];

    const int bid  = blockIdx.x;
    const int b    = bid / 98;            // 98 tiles per image (14 x 7)
    const int tile = bid - b * 98;
    const int th   = tile / 7;
    const int tw   = tile - th * 7;
    const int t    = threadIdx.x;
    const int lane = t & 63;
    const int wid  = t >> 6;              // 0..3 : o-quarter

    // staging roles
    const int sc    = t >> 6;             // 0..3
    const int spix  = t & 63;
    const int sph   = spix / 10, spw = spix - sph * 10;
    const bool svalid = (spix < NPIX);
    const int hg = th * TH - 1 + sph;
    const int wg = tw * TW - 1 + spw;
    const bool inb = svalid && (hg >= 0) && (hg < HW) && (wg >= 0) && (wg < HW);
    const size_t xbase = (size_t)b * CIN * L_ + (size_t)hg * HW + wg;

    // MFMA lane invariants
    const int q   = lane >> 4;
    const int r15 = lane & 15;
    int P[2];
#pragma unroll
    for (int mi = 0; mi < 2; mi++) {
        int arow = mi * 16 + r15;
        int lh = arow >> 3, lw = arow & 7;
        P[mi] = (lh * HALO_W + lw) * 16 + q * G8_CSTR;
    }
    const int obase = wid * 32 + r15;

    // B running pointers (bytes), dense layout: addr(kstep, ni) =
    //   Bp + (kstep*128 + obase + ni*16)*64 + q*16 ; per-step stride 8192B.
    u64 pa0 = (u64)Bp + ((u64)obase * 64) + ((u64)q * 16);
    u64 pa1 = pa0 + 1024;                 // +16 o

    // x running pointers: chunk ch loads channels (ch+1)*8 + {sc, 4+sc}
    const u64 xadv = inb ? (u64)8 * L_ * 4 : 0;
    u64 px0 = inb ? ((u64)x + ((u64)xbase + (size_t)sc * L_) * 4)       : (u64)x;
    u64 px1 = inb ? ((u64)x + ((u64)xbase + (size_t)(4 + sc) * L_) * 4) : (u64)x;

    f32x4 acc[2][2];
#pragma unroll
    for (int mi = 0; mi < 2; mi++)
#pragma unroll
        for (int ni = 0; ni < 2; ni++) acc[mi][ni] = (f32x4){0.f, 0.f, 0.f, 0.f};

    // ---- chunk-0 x loads + eval (no asm B loads in flight yet) ----
    float xa, xb;
    XLOAD(xa, px0);
    XLOAD(xb, px1);
    px0 += xadv; px1 += xadv;            // now point at chunk-1 channels
    asm volatile("s_waitcnt vmcnt(0)");
    __builtin_amdgcn_sched_barrier(0);
    if (svalid) {
        float va = inb ? xa : 0.0f, vb = inb ? xb : 0.0f;
        eval_store(va, &lds[sc * G8_CSTR + spix * 16],
                   &lds[G8_SIZE + (sc >> 1) * G8_CSTR + spix * 16 + (sc & 1) * 8]);
        eval_store(vb, &lds[(4 + sc) * G8_CSTR + spix * 16],
                   &lds[G8_SIZE + ((4 + sc) >> 1) * G8_CSTR + spix * 16 + ((4 + sc) & 1) * 8]);
    }
    asm volatile("s_waitcnt lgkmcnt(0)");
    __builtin_amdgcn_s_barrier();

    // ---- B pipeline prologue: 9 pairs in flight ----
    bf16x8 breg0[9], breg1[9];
#pragma unroll
    for (int s = 0; s < 9; s++) {
        BLOAD(breg0[s], pa0);
        BLOAD(breg1[s], pa1);
        pa0 += 8192; pa1 += 8192;
    }

#pragma unroll 1
    for (int ch = 0; ch < 8; ch++) {
        // x pair for chunk ch+1 (dummy reload on ch==7 keeps vmcnt uniform)
        XLOAD(xa, px0);
        XLOAD(xb, px1);
        px0 += xadv; px1 += xadv;

        char* abuf = &lds[(ch & 1) * BUF_SIZE];
        char* nbuf = &lds[((ch + 1) & 1) * BUF_SIZE];

        bf16x8 areg0[3], areg1[3];
        auto aread = [&](int s, bf16x8& a0, bf16x8& a1) {
            int k = s / 3, ph = s - k * 3;
            int ki = k / 3, kj = k - ki * 3;
            int poff = (ki * HALO_W + kj) * 16;
            int aoff = (ph == 2) ? (G8_SIZE + poff) : (ph * 4 * G8_CSTR + poff);
            a0 = *reinterpret_cast<const bf16x8*>(abuf + P[0] + aoff);
            a1 = *reinterpret_cast<const bf16x8*>(abuf + P[1] + aoff);
        };
        aread(0, areg0[0], areg1[0]);
        aread(1, areg0[1], areg1[1]);

#pragma unroll
        for (int s = 0; s < 27; s++) {
            if (s + 2 < 27) aread(s + 2, areg0[(s + 2) % 3], areg1[(s + 2) % 3]);
            // vmcnt(16): formally guarantees the consumed pair has retired
            // (accounts for the chunk-top x-pair ahead of it in the queue).
            asm volatile("s_waitcnt vmcnt(16)");
            __builtin_amdgcn_sched_barrier(0);
            const int bs = s % 9;
            bf16x8 af0 = areg0[s % 3], af1 = areg1[s % 3];
            acc[0][0] = __builtin_amdgcn_mfma_f32_16x16x32_bf16(af0, breg0[bs], acc[0][0], 0, 0, 0);
            acc[1][0] = __builtin_amdgcn_mfma_f32_16x16x32_bf16(af1, breg0[bs], acc[1][0], 0, 0, 0);
            acc[0][1] = __builtin_amdgcn_mfma_f32_16x16x32_bf16(af0, breg1[bs], acc[0][1], 0, 0, 0);
            acc[1][1] = __builtin_amdgcn_mfma_f32_16x16x32_bf16(af1, breg1[bs], acc[1][1], 0, 0, 0);
            // refill consumed slot for step s+9 (tail reads run past Bp end
            // into the 72KB ws pad; values never consumed)
            BLOAD(breg0[bs], pa0);
            BLOAD(breg1[bs], pa1);
            pa0 += 8192; pa1 += 8192;
        }

        // x pair was retired by the step-8 wait; values are valid here.
        if (ch < 7 && svalid) {
            float va = inb ? xa : 0.0f, vb = inb ? xb : 0.0f;
            eval_store(va, &nbuf[sc * G8_CSTR + spix * 16],
                       &nbuf[G8_SIZE + (sc >> 1) * G8_CSTR + spix * 16 + (sc & 1) * 8]);
            eval_store(vb, &nbuf[(4 + sc) * G8_CSTR + spix * 16],
                       &nbuf[G8_SIZE + ((4 + sc) >> 1) * G8_CSTR + spix * 16 + ((4 + sc) & 1) * 8]);
        }
        asm volatile("s_waitcnt lgkmcnt(0)");
        __builtin_amdgcn_s_barrier();
    }

    asm volatile("s_waitcnt vmcnt(0)");   // drain tail prefetches

    // ---- epilogue ----
#pragma unroll
    for (int ni = 0; ni < 2; ni++) {
        int o = obase + ni * 16;
        float bv = bias[o];
#pragma unroll
        for (int mi = 0; mi < 2; mi++) {
            int crow = mi * 16 + q * 4;
            int lh = crow >> 3, lw = crow & 7;
            int lg = (th * TH + lh) * HW + tw * TW + lw;
            float4 v;
            v.x = acc[mi][ni][0] + bv;
            v.y = acc[mi][ni][1] + bv;
            v.z = acc[mi][ni][2] + bv;
            v.w = acc[mi][ni][3] + bv;
            *reinterpret_cast<float4*>(&out[(size_t)(b * COUT + o) * L_ + lg]) = v;
        }
    }
}

// Partial sums per (b,o) slab.
__global__ __launch_bounds__(256) void k_part(const float* __restrict__ s,
                                              float* __restrict__ part) {
    const int slab = blockIdx.x;
    const float4* p4 = reinterpret_cast<const float4*>(s + (size_t)slab * L_);
    const int t = threadIdx.x;
    float sum = 0.f, sq = 0.f;
    for (int i = t; i < L_ / 4; i += 256) {
        float4 v = p4[i];
        sum += v.x + v.y + v.z + v.w;
        sq  += v.x * v.x + v.y * v.y + v.z * v.z + v.w * v.w;
    }
    __shared__ float rs[256], rq[256];
    rs[t] = sum; rq[t] = sq;
    __syncthreads();
    for (int off = 128; off > 0; off >>= 1) {
        if (t < off) { rs[t] += rs[t + off]; rq[t] += rq[t + off]; }
        __syncthreads();
    }
    if (t == 0) { part[slab] = rs[0]; part[1024 + slab] = rq[0]; }
}

__global__ __launch_bounds__(128) void k_final(const float* __restrict__ part,
                                               const float* __restrict__ gamma,
                                               const float* __restrict__ beta,
                                               float* __restrict__ ss) {
    int o = threadIdx.x;
    float sum = 0.f, sq = 0.f;
#pragma unroll
    for (int b = 0; b < 8; b++) {
        sum += part[b * COUT + o];
        sq  += part[1024 + b * COUT + o];
    }
    float n = (float)(8 * L_);
    float mean = sum / n;
    float var  = sq / n - mean * mean;
    float scale = gamma[o] * rsqrtf(var + 1e-5f);
    ss[o]        = scale;
    ss[COUT + o] = beta[o] - mean * scale;
}

__global__ __launch_bounds__(256) void k_norm(float* __restrict__ out,
                                              const float* __restrict__ ss) {
    const int n4 = 8 * COUT * L_ / 4;
    for (int i = blockIdx.x * 256 + threadIdx.x; i < n4; i += gridDim.x * 256) {
        int o = ((i * 4) / L_) & (COUT - 1);
        float sc = ss[o], sh = ss[COUT + o];
        float4 v = reinterpret_cast<float4*>(out)[i];
        v.x = fmaf(v.x, sc, sh);
        v.y = fmaf(v.y, sc, sh);
        v.z = fmaf(v.z, sc, sh);
        v.w = fmaf(v.w, sc, sh);
        reinterpret_cast<float4*>(out)[i] = v;
    }
}

extern "C" void kernel_launch(void* const* d_in, const int* in_sizes, int n_in,
                              void* d_out, int out_size, void* d_ws, size_t ws_size,
                              hipStream_t stream) {
    const float* x     = (const float*)d_in[0];
    const float* cp    = (const float*)d_in[1];
    const float* w     = (const float*)d_in[2];
    const float* bias  = (const float*)d_in[3];
    const float* gamma = (const float*)d_in[4];
    const float* beta  = (const float*)d_in[5];
    float* out = (float*)d_out;

    unsigned short* Bp = (unsigned short*)d_ws;
    float* part = (float*)((char*)d_ws + PART_OFF);
    float* ss   = (float*)((char*)d_ws + SS_OFF);

    k_packB<<<(COUT * KTOT + 255) / 256, 256, 0, stream>>>(cp, w, Bp);
    k_main<<<8 * 98, 256, 0, stream>>>(x, Bp, bias, out);
    k_part<<<1024, 256, 0, stream>>>(out, part);
    k_final<<<1, 128, 0, stream>>>(part, gamma, beta, ss);
    k_norm<<<2048, 256, 0, stream>>>(out, ss);
}

// Round 7
// 86.810 us; speedup vs baseline: 2.8168x; 1.5910x over previous
//
#include <hip/hip_runtime.h>
#include <math.h>

#define CIN   64
#define COUT  128
#define HW    56
#define L_    3136
#define KTOT  6912
#define TH    8            // tile rows
#define TW    8            // tile cols
#define HALO_W 10
#define NPIX  100          // 10 x 10 halo pixels
#define CSTR  (NPIX*16)    // 1600 B per channel record stripe
#define G8_SIZE (8*CSTR)   // 12800
#define G4_SIZE (4*CSTR)   // 6400
#define BUF_SIZE (G8_SIZE+G4_SIZE) // 19200

#define BP_BYTES (COUT * KTOT * 2)        // 1,769,472
#define PART_OFF BP_BYTES                 // no pad needed: B pointers wrap
#define SS_OFF   (PART_OFF + 2048 * 4)

typedef __attribute__((ext_vector_type(8))) short bf16x8;
typedef __attribute__((ext_vector_type(4))) float f32x4;
typedef unsigned long long u64;

#define BLOAD(dst, addr) \
    asm volatile("global_load_dwordx4 %0, %1, off" : "=v"(dst) : "v"(addr))
#define XLOAD(dst, addr) \
    asm volatile("global_load_dword %0, %1, off" : "=v"(dst) : "v"(addr))

__device__ __forceinline__ unsigned short f2bf(float f) {
    unsigned int u = __float_as_uint(f);
    return (unsigned short)((u + 0x7FFFu + ((u >> 16) & 1u)) >> 16);   // RNE
}
__device__ __forceinline__ unsigned int pk2(float a, float b) {
    return (unsigned int)f2bf(a) | ((unsigned int)f2bf(b) << 16);
}

// Reference basis for one pixel: g8rec (16B) = cubic weights scattered to
// slots 0..7; g4half (8B) = {f8, f9, f10, raw x} bf16.
__device__ __forceinline__ void eval_store(float xv, char* g8rec, char* g4half) {
    float u  = 1.0f / (1.0f + __expf(-xv));
    float tt = u * 11.0f;
    int s = (int)floorf(tt);
    s = (s > 10) ? 10 : s;
    float xf  = tt - (float)s;
    float x2  = xf * xf, x3 = x2 * xf;
    float omx = 1.0f - xf;
    const float i6 = 1.0f / 6.0f;
    float w3 = x3 * i6;
    float w2 = fmaf(fmaf(fmaf(-3.0f, xf, 3.0f), xf, 3.0f), xf, 1.0f) * i6;
    float w1 = fmaf(fmaf(3.0f, xf, -6.0f), x2, 4.0f) * i6;
    float w0 = omx * omx * omx * i6;

    *reinterpret_cast<uint4*>(g8rec) = (uint4){0u, 0u, 0u, 0u};
    unsigned short* rec = reinterpret_cast<unsigned short*>(g8rec);
    {
        int j;
        j = s - 3; if (j >= 0 && j < 8) rec[j] = f2bf(w0);
        j = s - 2; if (j >= 0 && j < 8) rec[j] = f2bf(w1);
        j = s - 1; if (j >= 0 && j < 8) rec[j] = f2bf(w2);
        j = s;     if (j >= 0 && j < 8) rec[j] = f2bf(w3);
    }
    float y = tt - 8.0f;
    float f8 = 0.0f;
    f8 = (s == 8)  ? 0.5f * y * y : f8;
    f8 = (s == 9)  ? 0.5f * fmaf(-2.0f * y, y, fmaf(6.0f, y, -3.0f)) : f8;
    f8 = (s == 10) ? 0.5f * (3.0f - y) * (3.0f - y) : f8;
    float z = tt - 9.0f;
    float f9 = 0.0f;
    f9 = (s == 9)  ? z : f9;
    f9 = (s == 10) ? 2.0f - z : f9;
    float f10 = (s == 10) ? 1.0f : 0.0f;
    *reinterpret_cast<uint2*>(g4half) = make_uint2(pk2(f8, f9), pk2(f10, xv));
}

// Pack B in DENSE per-(kstep,o) 64B units: Bp[kstep][o][e32] (same as R6).
__global__ __launch_bounds__(256) void k_packB(const float* __restrict__ cp,
                                               const float* __restrict__ w,
                                               unsigned short* __restrict__ Bp) {
    int idx = blockIdx.x * 256 + threadIdx.x;
    if (idx >= COUT * KTOT) return;
    int kstep = idx >> 12;
    int rem   = idx & 4095;
    int o     = rem >> 5;
    int e32   = rem & 31;
    int ch = kstep / 27, sc = kstep - ch * 27;
    int ktap = sc / 3, ph = sc - ktap * 3;
    int c, n;
    if (ph < 2) { c = ch * 8 + ph * 4 + (e32 >> 3); n = e32 & 7; }
    else        { int sub = e32 & 7; c = ch * 8 + (e32 >> 3) * 2 + (sub >> 2); n = 8 + (sub & 3); }
    float v;
    if (n < 11) v = cp[(((size_t)o * CIN + c) * 9 + ktap) * 11 + n];
    else        v = w[((size_t)o * CIN + c) * 9 + ktap];
    Bp[idx] = f2bf(v);
}

__global__ __launch_bounds__(256, 2) void k_main(const float* __restrict__ x,
                                                 const unsigned short* __restrict__ Bp,
                                                 const float* __restrict__ bias,
                                                 float* __restrict__ out) {
    __shared__ char lds[2 * BUF_SIZE];

    const int bid  = blockIdx.x;
    const int b    = bid / 49;            // 49 tiles per image (7 x 7 of 8x8)
    const int tile = bid - b * 49;
    const int th   = tile / 7;
    const int tw   = tile - th * 7;
    const int t    = threadIdx.x;
    const int lane = t & 63;
    const int wid  = t >> 6;              // 0..3 : o-quarter

    // ---- staging roles: 800 (pixel,channel) pairs per chunk, 4 slots/thread
    //      slot r: c = 2r + (t>=100), pixel p = t%100 (valid for t<200) ----
    const bool valid = (t < 200);
    const int p    = (t < 100) ? t : (t - 100);
    const int hi100 = (t >= 100) ? 1 : 0;
    const int ph_  = p / 10, pw_ = p - ph_ * 10;
    const int hg = th * TH - 1 + ph_;
    const int wg = tw * TW - 1 + pw_;
    const bool inb = valid && (hg >= 0) && (hg < HW) && (wg >= 0) && (wg < HW);
    const u64 xadv = inb ? (u64)8 * L_ * 4 : 0;
    u64 px[4];
#pragma unroll
    for (int r = 0; r < 4; r++) {
        int c0 = 2 * r + hi100;
        px[r] = inb ? ((u64)x + (((u64)b * CIN + c0) * L_ + (u64)hg * HW + wg) * 4)
                    : (u64)x;
    }

    // ---- MFMA lane invariants ----
    const int q   = lane >> 4;
    const int r15 = lane & 15;
    int P[4];
#pragma unroll
    for (int mi = 0; mi < 4; mi++) {
        int lh = mi * 2 + (r15 >> 3);
        int lw = r15 & 7;
        P[mi] = (lh * HALO_W + lw) * 16 + q * CSTR;
    }
    const int obase = wid * 32 + r15;

    // B running pointers, dense layout; per-step stride 8192B, wrap at end.
    const u64 bend = (u64)Bp + BP_BYTES;
    u64 pa0 = (u64)Bp + ((u64)obase * 64) + ((u64)q * 16);
    u64 pa1 = pa0 + 1024;                 // +16 o

    f32x4 acc[4][2];
#pragma unroll
    for (int mi = 0; mi < 4; mi++)
#pragma unroll
        for (int ni = 0; ni < 2; ni++) acc[mi][ni] = (f32x4){0.f, 0.f, 0.f, 0.f};

    // ---- chunk-0 x loads + eval ----
    float xa[4];
    XLOAD(xa[0], px[0]); XLOAD(xa[1], px[1]);
    XLOAD(xa[2], px[2]); XLOAD(xa[3], px[3]);
#pragma unroll
    for (int r = 0; r < 4; r++) px[r] += xadv;
    asm volatile("s_waitcnt vmcnt(0)");
    __builtin_amdgcn_sched_barrier(0);
    if (valid) {
#pragma unroll
        for (int r = 0; r < 4; r++) {
            float va = inb ? xa[r] : 0.0f;
            int c = 2 * r + hi100;
            eval_store(va, &lds[c * CSTR + p * 16],
                       &lds[G8_SIZE + r * CSTR + p * 16 + hi100 * 8]);
        }
    }
    asm volatile("s_waitcnt lgkmcnt(0)");
    __builtin_amdgcn_s_barrier();

    // ---- B pipeline prologue: 9 pairs in flight (no wrap possible yet) ----
    bf16x8 breg0[9], breg1[9];
#pragma unroll
    for (int s = 0; s < 9; s++) {
        BLOAD(breg0[s], pa0);
        BLOAD(breg1[s], pa1);
        pa0 += 8192; pa1 += 8192;
    }

#pragma unroll 1
    for (int ch = 0; ch < 8; ch++) {
        // x quad for chunk ch+1 (ch==7: reload same address, stays in bounds)
        XLOAD(xa[0], px[0]); XLOAD(xa[1], px[1]);
        XLOAD(xa[2], px[2]); XLOAD(xa[3], px[3]);
        if (ch < 7) {
#pragma unroll
            for (int r = 0; r < 4; r++) px[r] += xadv;
        }

        char* abuf = &lds[(ch & 1) * BUF_SIZE];
        char* nbuf = &lds[((ch + 1) & 1) * BUF_SIZE];

        bf16x8 areg[2][4];
        auto aread = [&](int s, bf16x8 (&a)[4]) {
            int k = s / 3, bp = s - k * 3;
            int ki = k / 3, kj = k - ki * 3;
            int poff = (ki * HALO_W + kj) * 16;
            int aoff = (bp == 2) ? (G8_SIZE + poff) : (bp * 4 * CSTR + poff);
#pragma unroll
            for (int mi = 0; mi < 4; mi++)
                a[mi] = *reinterpret_cast<const bf16x8*>(abuf + P[mi] + aoff);
        };
        aread(0, areg[0]);

#pragma unroll
        for (int s = 0; s < 27; s++) {
            if (s + 1 < 27) aread(s + 1, areg[(s + 1) & 1]);
            // 18 B + 4 x outstanding at chunk top; vmcnt(16) always guarantees
            // the consumed B pair has retired (newest 16 = last 8 refills).
            asm volatile("s_waitcnt vmcnt(16)");
            __builtin_amdgcn_sched_barrier(0);
            const int bs = s % 9;
#pragma unroll
            for (int mi = 0; mi < 4; mi++) {
                acc[mi][0] = __builtin_amdgcn_mfma_f32_16x16x32_bf16(areg[s & 1][mi], breg0[bs], acc[mi][0], 0, 0, 0);
                acc[mi][1] = __builtin_amdgcn_mfma_f32_16x16x32_bf16(areg[s & 1][mi], breg1[bs], acc[mi][1], 0, 0, 0);
            }
            // refill consumed slot for step s+9 (wraps past Bp end -> reloads
            // from start; values never consumed)
            BLOAD(breg0[bs], pa0);
            BLOAD(breg1[bs], pa1);
            pa0 += 8192; if (pa0 >= bend) pa0 -= BP_BYTES;
            pa1 += 8192; if (pa1 >= bend) pa1 -= BP_BYTES;
        }

        // x quad retired by step-26's vmcnt(16) (18 newest = next chunk's pairs)
        if (ch < 7 && valid) {
#pragma unroll
            for (int r = 0; r < 4; r++) {
                float va = inb ? xa[r] : 0.0f;
                int c = 2 * r + hi100;
                eval_store(va, &nbuf[c * CSTR + p * 16],
                           &nbuf[G8_SIZE + r * CSTR + p * 16 + hi100 * 8]);
            }
        }
        asm volatile("s_waitcnt lgkmcnt(0)");
        __builtin_amdgcn_s_barrier();
    }

    asm volatile("s_waitcnt vmcnt(0)");   // drain tail prefetches

    // ---- epilogue: C frag col (lane&15) -> o; row = mi*16 + q*4 + j -> l ----
#pragma unroll
    for (int ni = 0; ni < 2; ni++) {
        int o = obase + ni * 16;
        float bv = bias[o];
#pragma unroll
        for (int mi = 0; mi < 4; mi++) {
            int lh = mi * 2 + (q >> 1);
            int lw0 = (q & 1) * 4;
            int lg = (th * TH + lh) * HW + tw * TW + lw0;
            float4 v;
            v.x = acc[mi][ni][0] + bv;
            v.y = acc[mi][ni][1] + bv;
            v.z = acc[mi][ni][2] + bv;
            v.w = acc[mi][ni][3] + bv;
            *reinterpret_cast<float4*>(&out[(size_t)(b * COUT + o) * L_ + lg]) = v;
        }
    }
}

// Partial sums per (b,o) slab.
__global__ __launch_bounds__(256) void k_part(const float* __restrict__ s,
                                              float* __restrict__ part) {
    const int slab = blockIdx.x;
    const float4* p4 = reinterpret_cast<const float4*>(s + (size_t)slab * L_);
    const int t = threadIdx.x;
    float sum = 0.f, sq = 0.f;
    for (int i = t; i < L_ / 4; i += 256) {
        float4 v = p4[i];
        sum += v.x + v.y + v.z + v.w;
        sq  += v.x * v.x + v.y * v.y + v.z * v.z + v.w * v.w;
    }
    __shared__ float rs[256], rq[256];
    rs[t] = sum; rq[t] = sq;
    __syncthreads();
    for (int off = 128; off > 0; off >>= 1) {
        if (t < off) { rs[t] += rs[t + off]; rq[t] += rq[t + off]; }
        __syncthreads();
    }
    if (t == 0) { part[slab] = rs[0]; part[1024 + slab] = rq[0]; }
}

__global__ __launch_bounds__(128) void k_final(const float* __restrict__ part,
                                               const float* __restrict__ gamma,
                                               const float* __restrict__ beta,
                                               float* __restrict__ ss) {
    int o = threadIdx.x;
    float sum = 0.f, sq = 0.f;
#pragma unroll
    for (int b = 0; b < 8; b++) {
        sum += part[b * COUT + o];
        sq  += part[1024 + b * COUT + o];
    }
    float n = (float)(8 * L_);
    float mean = sum / n;
    float var  = sq / n - mean * mean;
    float scale = gamma[o] * rsqrtf(var + 1e-5f);
    ss[o]        = scale;
    ss[COUT + o] = beta[o] - mean * scale;
}

__global__ __launch_bounds__(256) void k_norm(float* __restrict__ out,
                                              const float* __restrict__ ss) {
    const int n4 = 8 * COUT * L_ / 4;
    for (int i = blockIdx.x * 256 + threadIdx.x; i < n4; i += gridDim.x * 256) {
        int o = ((i * 4) / L_) & (COUT - 1);
        float sc = ss[o], sh = ss[COUT + o];
        float4 v = reinterpret_cast<float4*>(out)[i];
        v.x = fmaf(v.x, sc, sh);
        v.y = fmaf(v.y, sc, sh);
        v.z = fmaf(v.z, sc, sh);
        v.w = fmaf(v.w, sc, sh);
        reinterpret_cast<float4*>(out)[i] = v;
    }
}

extern "C" void kernel_launch(void* const* d_in, const int* in_sizes, int n_in,
                              void* d_out, int out_size, void* d_ws, size_t ws_size,
                              hipStream_t stream) {
    const float* x     = (const float*)d_in[0];
    const float* cp    = (const float*)d_in[1];
    const float* w     = (const float*)d_in[2];
    const float* bias  = (const float*)d_in[3];
    const float* gamma = (const float*)d_in[4];
    const float* beta  = (const float*)d_in[5];
    float* out = (float*)d_out;

    unsigned short* Bp = (unsigned short*)d_ws;
    float* part = (float*)((char*)d_ws + PART_OFF);
    float* ss   = (float*)((char*)d_ws + SS_OFF);

    k_packB<<<(COUT * KTOT + 255) / 256, 256, 0, stream>>>(cp, w, Bp);
    k_main<<<8 * 49, 256, 0, stream>>>(x, Bp, bias, out);
    k_part<<<1024, 256, 0, stream>>>(out, part);
    k_final<<<1, 128, 0, stream>>>(part, gamma, beta, ss);
    k_norm<<<2048, 256, 0, stream>>>(out, ss);
}